// Round 1
// baseline (242.450 us; speedup 1.0000x reference)
//
#include <hip/hip_runtime.h>

// FourierFlow: out[t,n,i] = sum_j expm((M*omega + M0)*t)[i,j] * x[n,j]
// Inputs (setup_inputs order):
//   d_in[0] = x     (N=16384, 16) float32
//   d_in[1] = t     (T=512,)      float32
//   d_in[2] = omega (1,)          float32
//   d_in[3] = M     (16,16)       float32
//   d_in[4] = M0    (16,16)       float32
// Output: (T, N, 16) float32 = 134,217,728 elements (536.9 MB) -> write-BW bound.

#define MDIM 16
#define MELEMS 256

// ---------------- Kernel 1: batched 16x16 matrix exponential ----------------
// One block per time step. 256 threads, one per matrix element (i,j).
// General scaling-and-squaring + 12-term Horner-Taylor, all in LDS.
__global__ __launch_bounds__(256) void expm_kernel(
    const float* __restrict__ t,
    const float* __restrict__ omega,
    const float* __restrict__ M,
    const float* __restrict__ M0,
    float* __restrict__ E /* (T,16,16) */) {
  __shared__ float A[MELEMS];   // scaled generator B
  __shared__ float T[MELEMS];   // running result
  __shared__ int sshift;

  const int bt  = blockIdx.x;
  const int tid = threadIdx.x;
  const int i = tid >> 4;
  const int j = tid & 15;

  const float tv = t[bt];
  const float om = omega[0];
  float a = (M[tid] * om + M0[tid]) * tv;

  A[tid] = a;
  __syncthreads();

  // inf-norm -> scaling exponent s so that ||A/2^s|| <= 0.5
  if (tid == 0) {
    float nrm = 0.f;
    for (int r = 0; r < MDIM; ++r) {
      float rs = 0.f;
      for (int c = 0; c < MDIM; ++c) rs += fabsf(A[r * MDIM + c]);
      nrm = fmaxf(nrm, rs);
    }
    int s = 0;
    while (nrm > 0.5f && s < 40) { nrm *= 0.5f; ++s; }
    sshift = s;
  }
  __syncthreads();
  const int s = sshift;

  const float b = ldexpf(a, -s);
  const float ident = (i == j) ? 1.0f : 0.0f;
  A[tid] = b;
  T[tid] = ident;
  __syncthreads();

  // Horner-Taylor: for k = K..1: T = I + (B @ T) * (1/k)
  const int K = 12;
  for (int k = K; k >= 1; --k) {
    float acc = 0.f;
#pragma unroll
    for (int c = 0; c < MDIM; ++c) acc += A[i * MDIM + c] * T[c * MDIM + j];
    __syncthreads();           // everyone done reading T
    T[tid] = ident + acc * (1.0f / (float)k);
    __syncthreads();
  }

  // square s times: T = T @ T
  for (int k = 0; k < s; ++k) {
    float acc = 0.f;
#pragma unroll
    for (int c = 0; c < MDIM; ++c) acc += T[i * MDIM + c] * T[c * MDIM + j];
    __syncthreads();
    T[tid] = acc;
    __syncthreads();
  }

  E[(size_t)bt * MELEMS + tid] = T[tid];
}

// ---------------- Kernel 2: out[t,n,:] = E[t] @ x[n,:] ----------------
// grid = (N/64, T), block = 256. Each block: one t, 64 rows of x.
// Thread tid -> n_local = tid>>2, i4 = tid&3: computes output floats
// [i4*4, i4*4+4) for row n. Consecutive lanes write consecutive float4s
// -> fully coalesced 4 KB/wave stores.
__global__ __launch_bounds__(256) void apply_kernel(
    const float* __restrict__ E,  /* (T,16,16) */
    const float* __restrict__ x,  /* (N,16)    */
    float* __restrict__ out,      /* (T,N,16)  */
    int N) {
  __shared__ float Es[MELEMS];
  const int t = blockIdx.y;
  const int tid = threadIdx.x;
  Es[tid] = E[(size_t)t * MELEMS + tid];
  __syncthreads();

  const int nb = blockIdx.x * 64;
  const int n  = nb + (tid >> 2);
  const int i4 = tid & 3;

  const float4* xr = (const float4*)(x + (size_t)n * MDIM);
  const float4 x0 = xr[0], x1 = xr[1], x2 = xr[2], x3 = xr[3];

  float o[4];
#pragma unroll
  for (int k = 0; k < 4; ++k) {
    const float* Er = Es + (i4 * 4 + k) * MDIM;
    o[k] = Er[0]  * x0.x + Er[1]  * x0.y + Er[2]  * x0.z + Er[3]  * x0.w
         + Er[4]  * x1.x + Er[5]  * x1.y + Er[6]  * x1.z + Er[7]  * x1.w
         + Er[8]  * x2.x + Er[9]  * x2.y + Er[10] * x2.z + Er[11] * x2.w
         + Er[12] * x3.x + Er[13] * x3.y + Er[14] * x3.z + Er[15] * x3.w;
  }

  float4* op = (float4*)(out + (size_t)t * (size_t)N * MDIM + (size_t)nb * MDIM);
  op[tid] = make_float4(o[0], o[1], o[2], o[3]);
}

extern "C" void kernel_launch(void* const* d_in, const int* in_sizes, int n_in,
                              void* d_out, int out_size, void* d_ws, size_t ws_size,
                              hipStream_t stream) {
  const float* x     = (const float*)d_in[0];
  const float* t     = (const float*)d_in[1];
  const float* omega = (const float*)d_in[2];
  const float* M     = (const float*)d_in[3];
  const float* M0    = (const float*)d_in[4];
  float* out = (float*)d_out;

  const int N = in_sizes[0] / MDIM;   // 16384
  const int T = in_sizes[1];          // 512

  float* E = (float*)d_ws;            // T*256 floats = 512 KB

  expm_kernel<<<T, 256, 0, stream>>>(t, omega, M, M0, E);

  dim3 grid(N / 64, T);
  apply_kernel<<<grid, 256, 0, stream>>>(E, x, out, N);
}

// Round 2
// 126.951 us; speedup vs baseline: 1.9098x; 1.9098x over previous
//
#include <hip/hip_runtime.h>

// FourierFlow: out[t,n,i] = sum_j expm((M*omega + M0)*t)[i,j] * x[n,j]
// Inputs: x (16384,16) f32 | t (512,) f32 | omega (1,) f32 | M (16,16) f32 | M0 (16,16) f32
// Output: (512, 16384, 16) f32 = 536.9 MB -> write-BW bound (~80 us floor at 6.7 TB/s).

#define MDIM 16
#define MELEMS 256
#define RPT 8              // x-rows per thread in apply kernel
#define ROWS_PER_BLOCK 512 // 64 lane-groups * RPT

// ---------------- Kernel 1: batched 16x16 matrix exponential ----------------
// One block per time step, 256 threads (one per matrix element).
// Scaling-and-squaring + 12-term Horner-Taylor in LDS.
__global__ __launch_bounds__(256) void expm_kernel(
    const float* __restrict__ t,
    const float* __restrict__ omega,
    const float* __restrict__ M,
    const float* __restrict__ M0,
    float* __restrict__ E /* (T,16,16) */) {
  __shared__ float A[MELEMS];
  __shared__ float T[MELEMS];
  __shared__ float rowsum[MDIM];

  const int bt  = blockIdx.x;
  const int tid = threadIdx.x;
  const int i = tid >> 4;
  const int j = tid & 15;

  const float tv = t[bt];
  const float om = omega[0];
  const float a = (M[tid] * om + M0[tid]) * tv;

  // parallel inf-norm: row-sum via 16-lane shuffle butterfly, then max over rows
  float rs = fabsf(a);
  rs += __shfl_xor(rs, 1);
  rs += __shfl_xor(rs, 2);
  rs += __shfl_xor(rs, 4);
  rs += __shfl_xor(rs, 8);
  if (j == 0) rowsum[i] = rs;
  __syncthreads();
  float nrm = 0.f;
#pragma unroll
  for (int r = 0; r < MDIM; ++r) nrm = fmaxf(nrm, rowsum[r]);
  int s = 0;
  while (nrm > 0.5f && s < 40) { nrm *= 0.5f; ++s; }

  const float b = ldexpf(a, -s);
  const float ident = (i == j) ? 1.0f : 0.0f;
  A[tid] = b;
  T[tid] = ident;
  __syncthreads();

  // Horner-Taylor: for k = K..1: T = I + (B @ T) / k
  for (int k = 12; k >= 1; --k) {
    float acc = 0.f;
#pragma unroll
    for (int c = 0; c < MDIM; ++c) acc += A[i * MDIM + c] * T[c * MDIM + j];
    __syncthreads();
    T[tid] = ident + acc * (1.0f / (float)k);
    __syncthreads();
  }

  // square s times
  for (int k = 0; k < s; ++k) {
    float acc = 0.f;
#pragma unroll
    for (int c = 0; c < MDIM; ++c) acc += T[i * MDIM + c] * T[c * MDIM + j];
    __syncthreads();
    T[tid] = acc;
    __syncthreads();
  }

  E[(size_t)bt * MELEMS + tid] = T[tid];
}

// ---------------- Kernel 2: out[t,n,:] = E[t] @ x[n,:] ----------------
// grid = (N/512, T), block = 256. Thread (nl = tid>>2, i4 = tid&3) keeps its
// 4 E-rows in registers (loaded once from padded LDS, conflict-free) and
// streams RPT=8 x-rows: 64 reg-FMAs + one coalesced float4 store per row.
__global__ __launch_bounds__(256) void apply_kernel(
    const float* __restrict__ E,  /* (T,16,16) */
    const float* __restrict__ x,  /* (N,16)    */
    float* __restrict__ out,      /* (T,N,16)  */
    int N) {
  __shared__ __align__(16) float Es[MDIM * 20];  // rows padded to 20 floats
  const int t   = blockIdx.y;
  const int tid = threadIdx.x;
  {
    const int r = tid >> 4, c = tid & 15;
    Es[r * 20 + c] = E[(size_t)t * MELEMS + tid];
  }
  __syncthreads();

  const int i4 = tid & 3;
  const int nl = tid >> 2;

  // 4 E-rows -> 16 float4 registers (row stride 80 B keeps 16B alignment;
  // 4 distinct addrs per b128 land on 2 banks -> 2-way = free)
  float4 e[16];
#pragma unroll
  for (int k = 0; k < 4; ++k) {
    const float* row = Es + (i4 * 4 + k) * 20;
#pragma unroll
    for (int q = 0; q < 4; ++q) e[k * 4 + q] = *(const float4*)(row + q * 4);
  }

  const size_t nb = (size_t)blockIdx.x * ROWS_PER_BLOCK;
  const float4* __restrict__ xin = (const float4*)x;
  float4* __restrict__ op = (float4*)(out + ((size_t)t * N + nb) * MDIM);

#pragma unroll
  for (int k = 0; k < RPT; ++k) {
    const size_t n = nb + nl + (size_t)k * 64;
    const float4 x0 = xin[n * 4 + 0];
    const float4 x1 = xin[n * 4 + 1];
    const float4 x2 = xin[n * 4 + 2];
    const float4 x3 = xin[n * 4 + 3];

    float o[4];
#pragma unroll
    for (int r = 0; r < 4; ++r) {
      const float4 e0 = e[r * 4 + 0], e1 = e[r * 4 + 1];
      const float4 e2 = e[r * 4 + 2], e3 = e[r * 4 + 3];
      o[r] = e0.x * x0.x + e0.y * x0.y + e0.z * x0.z + e0.w * x0.w
           + e1.x * x1.x + e1.y * x1.y + e1.z * x1.z + e1.w * x1.w
           + e2.x * x2.x + e2.y * x2.y + e2.z * x2.z + e2.w * x2.w
           + e3.x * x3.x + e3.y * x3.y + e3.z * x3.z + e3.w * x3.w;
    }
    op[k * 256 + tid] = make_float4(o[0], o[1], o[2], o[3]);
  }
}

extern "C" void kernel_launch(void* const* d_in, const int* in_sizes, int n_in,
                              void* d_out, int out_size, void* d_ws, size_t ws_size,
                              hipStream_t stream) {
  const float* x     = (const float*)d_in[0];
  const float* t     = (const float*)d_in[1];
  const float* omega = (const float*)d_in[2];
  const float* M     = (const float*)d_in[3];
  const float* M0    = (const float*)d_in[4];
  float* out = (float*)d_out;

  const int N = in_sizes[0] / MDIM;   // 16384
  const int T = in_sizes[1];          // 512

  float* E = (float*)d_ws;            // T*256 floats = 512 KB

  expm_kernel<<<T, 256, 0, stream>>>(t, omega, M, M0, E);

  dim3 grid(N / ROWS_PER_BLOCK, T);
  apply_kernel<<<grid, 256, 0, stream>>>(E, x, out, N);
}

// Round 3
// 117.057 us; speedup vs baseline: 2.0712x; 1.0845x over previous
//
#include <hip/hip_runtime.h>
#include <math.h>

// FourierFlow: out[t,n,i] = sum_j expm((M*omega + M0)*t)[i,j] * x[n,j]
// Inputs: x (16384,16) f32 | t (512,) f32 | omega (1,) f32 | M (16,16) f32 | M0 (16,16) f32
// Output: (512, 16384, 16) f32 = 536.9 MB -> write-BW bound (~85 us floor at 6.7 TB/s).

#define MDIM 16
#define MELEMS 256
#define RPT 8              // x-rows per thread in apply kernel
#define ROWS_PER_BLOCK 512 // 64 lane-groups * RPT

// ---------------- Kernel 1: batched 16x16 matrix exponential ----------------
// One block per time step, 256 threads (one per matrix element).
// Scaling-and-squaring + 8-term Horner-Taylor in LDS (||B||<=0.5 -> err ~2e-9).
__global__ __launch_bounds__(256) void expm_kernel(
    const float* __restrict__ t,
    const float* __restrict__ omega,
    const float* __restrict__ M,
    const float* __restrict__ M0,
    float* __restrict__ E /* (T,16,16) */) {
  __shared__ float A[MELEMS];
  __shared__ float T[MELEMS];
  __shared__ float rowsum[MDIM];

  const int bt  = blockIdx.x;
  const int tid = threadIdx.x;
  const int i = tid >> 4;
  const int j = tid & 15;

  const float tv = t[bt];
  const float om = omega[0];
  const float a = (M[tid] * om + M0[tid]) * tv;

  // parallel inf-norm: row-sum via 16-lane shuffle butterfly, then max over rows
  float rs = fabsf(a);
  rs += __shfl_xor(rs, 1);
  rs += __shfl_xor(rs, 2);
  rs += __shfl_xor(rs, 4);
  rs += __shfl_xor(rs, 8);
  if (j == 0) rowsum[i] = rs;
  __syncthreads();
  float nrm = 0.f;
#pragma unroll
  for (int r = 0; r < MDIM; ++r) nrm = fmaxf(nrm, rowsum[r]);
  // scaling exponent: nrm / 2^s <= 0.5
  int s = (nrm > 1e-30f) ? (ilogbf(nrm) + 2) : 0;
  if (s < 0) s = 0;

  const float b = ldexpf(a, -s);
  const float ident = (i == j) ? 1.0f : 0.0f;
  A[tid] = b;
  T[tid] = ident;
  __syncthreads();

  // Horner-Taylor: for k = K..1: T = I + (B @ T) / k
  for (int k = 8; k >= 1; --k) {
    float acc = 0.f;
#pragma unroll
    for (int c = 0; c < MDIM; ++c) acc += A[i * MDIM + c] * T[c * MDIM + j];
    __syncthreads();
    T[tid] = ident + acc * (1.0f / (float)k);
    __syncthreads();
  }

  // square s times
  for (int k = 0; k < s; ++k) {
    float acc = 0.f;
#pragma unroll
    for (int c = 0; c < MDIM; ++c) acc += T[i * MDIM + c] * T[c * MDIM + j];
    __syncthreads();
    T[tid] = acc;
    __syncthreads();
  }

  E[(size_t)bt * MELEMS + tid] = T[tid];
}

// ---------------- Kernel 2: out[t,n,:] = E[t] @ x[n,:] ----------------
// grid = (N/512, T), block = 256. Thread (nl = tid>>2, i4 = tid&3) keeps its
// 4 E-rows in registers and streams 8 x-rows through an explicit 2-deep
// double buffer: loads for row k+1 are issued BEFORE the store of row k, so
// counted vmcnt waits on the (L1-hit) x loads never drain the slow HBM
// stores (vmcnt decrements in issue order). Live x regs capped at 2 rows.
__global__ __launch_bounds__(256, 4) void apply_kernel(
    const float* __restrict__ E,  /* (T,16,16) */
    const float* __restrict__ x,  /* (N,16)    */
    float* __restrict__ out,      /* (T,N,16)  */
    int N) {
  __shared__ __align__(16) float Es[MDIM * 20];  // rows padded to 20 floats
  const int t   = blockIdx.y;
  const int tid = threadIdx.x;
  {
    const int r = tid >> 4, c = tid & 15;
    Es[r * 20 + c] = E[(size_t)t * MELEMS + tid];
  }
  __syncthreads();

  const int i4 = tid & 3;
  const int nl = tid >> 2;

  // 4 E-rows -> 16 float4 registers
  float4 e[16];
#pragma unroll
  for (int k = 0; k < 4; ++k) {
    const float* row = Es + (i4 * 4 + k) * 20;
#pragma unroll
    for (int q = 0; q < 4; ++q) e[k * 4 + q] = *(const float4*)(row + q * 4);
  }

  const size_t nb = (size_t)blockIdx.x * ROWS_PER_BLOCK;
  const float4* __restrict__ xin = (const float4*)x;
  float4* __restrict__ op = (float4*)(out + ((size_t)t * N + nb) * MDIM);

  float4 xa0, xa1, xa2, xa3, xb0, xb1, xb2, xb3;

#define LOADX(d0, d1, d2, d3, k) do {                         \
    const size_t base = (nb + nl + (size_t)(k) * 64) * 4;     \
    d0 = xin[base + 0]; d1 = xin[base + 1];                   \
    d2 = xin[base + 2]; d3 = xin[base + 3];                   \
  } while (0)

#define DOT(o, x0, x1, x2, x3) do {                                        \
    _Pragma("unroll")                                                      \
    for (int r = 0; r < 4; ++r) {                                          \
      const float4 e0 = e[r * 4 + 0], e1 = e[r * 4 + 1];                   \
      const float4 e2 = e[r * 4 + 2], e3 = e[r * 4 + 3];                   \
      o[r] = e0.x * x0.x + e0.y * x0.y + e0.z * x0.z + e0.w * x0.w         \
           + e1.x * x1.x + e1.y * x1.y + e1.z * x1.z + e1.w * x1.w         \
           + e2.x * x2.x + e2.y * x2.y + e2.z * x2.z + e2.w * x2.w         \
           + e3.x * x3.x + e3.y * x3.y + e3.z * x3.z + e3.w * x3.w;        \
    }                                                                      \
  } while (0)

  LOADX(xa0, xa1, xa2, xa3, 0);
#pragma unroll
  for (int k = 0; k < RPT; k += 2) {
    float o[4];
    // even row (in xa): prefetch k+1 into xb BEFORE storing row k
    if (k + 1 < RPT) LOADX(xb0, xb1, xb2, xb3, k + 1);
    DOT(o, xa0, xa1, xa2, xa3);
    op[k * 256 + tid] = make_float4(o[0], o[1], o[2], o[3]);
    // odd row (in xb): prefetch k+2 into xa BEFORE storing row k+1
    if (k + 2 < RPT) LOADX(xa0, xa1, xa2, xa3, k + 2);
    DOT(o, xb0, xb1, xb2, xb3);
    op[(k + 1) * 256 + tid] = make_float4(o[0], o[1], o[2], o[3]);
  }
#undef LOADX
#undef DOT
}

extern "C" void kernel_launch(void* const* d_in, const int* in_sizes, int n_in,
                              void* d_out, int out_size, void* d_ws, size_t ws_size,
                              hipStream_t stream) {
  const float* x     = (const float*)d_in[0];
  const float* t     = (const float*)d_in[1];
  const float* omega = (const float*)d_in[2];
  const float* M     = (const float*)d_in[3];
  const float* M0    = (const float*)d_in[4];
  float* out = (float*)d_out;

  const int N = in_sizes[0] / MDIM;   // 16384
  const int T = in_sizes[1];          // 512

  float* E = (float*)d_ws;            // T*256 floats = 512 KB

  expm_kernel<<<T, 256, 0, stream>>>(t, omega, M, M0, E);

  dim3 grid(N / ROWS_PER_BLOCK, T);
  apply_kernel<<<grid, 256, 0, stream>>>(E, x, out, N);
}